// Round 12
// baseline (337.256 us; speedup 1.0000x reference)
//
#include <hip/hip_runtime.h>
#include <math.h>

// ---------------------------------------------------------------------------
// R11 (3rd submit; both prior benches were GPUAcquisitionTimeout, never ran):
//     mega-kernel with SOFTWARE global barrier (no cooperative API).
//     Measured lessons:
//       R5: LDS/flat atomic feature accumulation = 183 us/layer. Never.
//       R6: node-exact global scatter = 260 us (WRITE 194 MB, 15x ampl).
//       R7: 42 B scatter runs -> 4.7x write ampl (60 MB).
//       R8: 196-block kernels = grid starvation (48.9 us).
//       R9: 225.6 us best; setup_scatter 48-52 us (WRITE 39-55 MB);
//           csr round-trip re-read 2x by downstream layers.
//       R10: hipLaunchCooperativeKernel never ran (zeroed-ws err 0.27 =
//           max|ref|, poisoned-ws err 468 = poison -> out never written;
//           API-level launch failure). Fusion idea untested.
//     Changes vs R10: grid.sync -> hand-rolled agent-scope barrier
//       (atomic ACQ_REL arrive + acquire spin, s_sleep poll), normal launch.
//       Co-residency guaranteed: 48.5 KB LDS (3/CU), launch_bounds(512,4)
//       caps VGPR 128 (2/CU) -> 512 slots >= 391 blocks; 49/64 per XCD.
//       Barrier counter zeroed by the gcur memset every graph replay.
//     Pipeline: memset + setup_scatter + mega. 2 kernels.
// ---------------------------------------------------------------------------

#define CHUNK    32768    // edges per scatter block
#define BW       256      // nodes per bucket (dst >> 8)
#define NBMAX    400      // >= NB = 391
#define MAXB_RAW 9216     // raw edges clamp per bucket (mean 8193, +11 sigma)
#define MAXB_PAD 9984     // padded rows clamp (raw + 256*3)
#define REGION   9472     // fixed region stride (ints), 16B-aligned

typedef _Float16 half8 __attribute__((ext_vector_type(8)));

static __device__ __forceinline__ float sigmoidf_(float x) {
    return 1.0f / (1.0f + expf(-x));
}

// agent-scope global barrier: each block arrives once; all spin to target.
// Generation thresholds (target = gen*nblocks) avoid counter resets.
static __device__ __forceinline__ void gbar(int* bar, int target) {
    __syncthreads();
    if (threadIdx.x == 0) {
        __threadfence();   // belt-and-braces: order non-atomic stores
        __hip_atomic_fetch_add(bar, 1, __ATOMIC_ACQ_REL, __HIP_MEMORY_SCOPE_AGENT);
        while (__hip_atomic_load(bar, __ATOMIC_ACQUIRE, __HIP_MEMORY_SCOPE_AGENT) < target)
            __builtin_amdgcn_s_sleep(32);
    }
    __syncthreads();
}

// ---- fused: transform1 (blocks [0,nbT)) + hist/reserve/scatter -----------
__global__ __launch_bounds__(512)
void setup_scatter_kernel(const float* __restrict__ x, const float* __restrict__ Wrel,
                          const float* __restrict__ bias, const float* __restrict__ Wroot,
                          _Float16* __restrict__ t1, _Float16* __restrict__ z1,
                          const int* __restrict__ src, const int* __restrict__ dst,
                          int* __restrict__ gcur, unsigned* __restrict__ stage,
                          int N, int E, int NB, int nbT) {
    __shared__ float sWr[128], sWo[128], sb[8];
    __shared__ int s_hist[NBMAX];
    __shared__ int s_cur[NBMAX];
    int tid = threadIdx.x, blk = blockIdx.x;

    if (blk < nbT) {
        // ---- transform: t1 = x@Wr1, z1 = x@Wo1 + b1 ----
        if (tid < 128) { sWr[tid] = Wrel[tid]; sWo[tid] = Wroot[tid]; }
        if (tid >= 128 && tid < 136) sb[tid - 128] = bias[tid - 128];
        __syncthreads();
        int node = blk * 512 + tid;
        if (node >= N) return;
        const float4* x4 = (const float4*)x;
        float xv[16];
#pragma unroll
        for (int k = 0; k < 4; ++k) {
            float4 v = x4[node * 4 + k];
            xv[4 * k] = v.x; xv[4 * k + 1] = v.y; xv[4 * k + 2] = v.z; xv[4 * k + 3] = v.w;
        }
        float ta[8], za[8];
#pragma unroll
        for (int j = 0; j < 8; ++j) { ta[j] = 0.0f; za[j] = sb[j]; }
#pragma unroll
        for (int f = 0; f < 16; ++f) {
            float xf = xv[f];
#pragma unroll
            for (int j = 0; j < 8; ++j) {
                ta[j] += xf * sWr[f * 8 + j];
                za[j] += xf * sWo[f * 8 + j];
            }
        }
        half8 th, zh;
#pragma unroll
        for (int j = 0; j < 8; ++j) { th[j] = (_Float16)ta[j]; zh[j] = (_Float16)za[j]; }
        ((half8*)t1)[node] = th;
        ((half8*)z1)[node] = zh;
    } else {
        // ---- per-chunk hist -> global reserve -> LDS-cursor scatter ----
        int chunk = blk - nbT;
        int base = chunk * CHUNK;
        int cnt = E - base; if (cnt > CHUNK) cnt = CHUNK;
        for (int i = tid; i < NB; i += 512) s_hist[i] = 0;
        __syncthreads();
        if (cnt == CHUNK) {
            const int4* d4 = (const int4*)(dst + base);
#pragma unroll
            for (int k = 0; k < CHUNK / 2048; ++k) {
                int4 d = d4[k * 512 + tid];
                atomicAdd(&s_hist[d.x >> 8], 1);
                atomicAdd(&s_hist[d.y >> 8], 1);
                atomicAdd(&s_hist[d.z >> 8], 1);
                atomicAdd(&s_hist[d.w >> 8], 1);
            }
        } else {
            for (int i = tid; i < cnt; i += 512) atomicAdd(&s_hist[dst[base + i] >> 8], 1);
        }
        __syncthreads();
        for (int i = tid; i < NB; i += 512) {
            int hh = s_hist[i];
            s_cur[i] = i * REGION + atomicAdd(&gcur[i], hh);
        }
        __syncthreads();
        if (cnt == CHUNK) {
            const int4* d4 = (const int4*)(dst + base);
            const int4* s4 = (const int4*)(src + base);
#pragma unroll
            for (int k = 0; k < CHUNK / 2048; ++k) {
                int4 d = d4[k * 512 + tid];
                int4 s = s4[k * 512 + tid];
                int dd[4] = {d.x, d.y, d.z, d.w};
                int ss[4] = {s.x, s.y, s.z, s.w};
#pragma unroll
                for (int j = 0; j < 4; ++j) {
                    int pos = atomicAdd(&s_cur[dd[j] >> 8], 1);
                    stage[pos] = ((unsigned)(dd[j] & 255) << 17) | (unsigned)ss[j];
                }
            }
        } else {
            for (int i = tid; i < cnt; i += 512) {
                int d = dst[base + i], s = src[base + i];
                int pos = atomicAdd(&s_cur[d >> 8], 1);
                stage[pos] = ((unsigned)(d & 255) << 17) | (unsigned)s;
            }
        }
    }
}

// ---- mega: sort-to-LDS, 3 GCN layers with LDS indices, software barriers -
__global__ __launch_bounds__(512, 4)
void mega_kernel(const unsigned* __restrict__ stage, const int* __restrict__ gcur,
                 int* __restrict__ bar,
                 const _Float16* __restrict__ t1, const _Float16* __restrict__ z1,
                 _Float16* __restrict__ h1, _Float16* __restrict__ t3,
                 _Float16* __restrict__ z3,
                 const float* __restrict__ W2r, const float* __restrict__ b2,
                 const float* __restrict__ W2o,
                 const float* __restrict__ W3r, const float* __restrict__ b3,
                 const float* __restrict__ W3o,
                 const float* __restrict__ fc1W, const float* __restrict__ fc1b,
                 const float* __restrict__ fc2W, const float* __restrict__ fc2b,
                 float* __restrict__ out, int N, int NB) {
    __shared__ int __attribute__((aligned(16))) s_out[MAXB_PAD];
    __shared__ int h[BW], hs[BW], curb[BW];
    __shared__ int s_scan[512];
    __shared__ float sW2r[128], sW2o[128], sW3r[128], sW3o[128], sb2[16], sb3[8];
    __shared__ float sW1[256], sb1[32], sW2m[32], sb2s[1];

    int b = blockIdx.x, tid = threadIdx.x;
    int beg = b * REGION;
    int tot = gcur[b]; if (tot > MAXB_RAW) tot = MAXB_RAW;

    if (tid < 128) { sW2r[tid] = W2r[tid]; sW2o[tid] = W2o[tid];
                     sW3r[tid] = W3r[tid]; sW3o[tid] = W3o[tid]; }
    if (tid < 256) sW1[tid] = fc1W[tid];
    if (tid < 32) { sb1[tid] = fc1b[tid]; sW2m[tid] = fc2W[tid]; }
    if (tid < 16) sb2[tid] = b2[tid];
    if (tid < 8)  sb3[tid] = b3[tid];
    if (tid == 0) sb2s[0] = fc2b[0];
    if (tid < BW) h[tid] = 0;
    __syncthreads();

    // pass 1: per-node histogram (coalesced region read)
    const uint4* st4 = (const uint4*)(stage + beg);
    int n4 = tot >> 2;
    for (int i = tid; i < n4; i += 512) {
        uint4 p = st4[i];
        atomicAdd(&h[p.x >> 17], 1); atomicAdd(&h[p.y >> 17], 1);
        atomicAdd(&h[p.z >> 17], 1); atomicAdd(&h[p.w >> 17], 1);
    }
    for (int i = (n4 << 2) + tid; i < tot; i += 512) atomicAdd(&h[stage[beg + i] >> 17], 1);
    __syncthreads();

    // exclusive scan of align4(deg) over 512-ladder (zeros above BW)
    int v = (tid < BW) ? ((h[tid] + 3) & ~3) : 0;
    s_scan[tid] = v;
    for (int off = 1; off < 512; off <<= 1) {
        __syncthreads();
        int t = (tid >= off) ? s_scan[tid - off] : 0;
        __syncthreads();
        s_scan[tid] += t;
    }
    __syncthreads();
    if (tid < BW) { int myS = s_scan[tid] - v; hs[tid] = myS; curb[tid] = myS; }
    __syncthreads();

    // pass 2: counting-sort scatter into LDS (region re-read, L2-hot)
    for (int i = tid; i < n4; i += 512) {
        uint4 p = st4[i];
        int pos;
        pos = atomicAdd(&curb[p.x >> 17], 1); s_out[pos] = (int)(p.x & 0x1FFFF);
        pos = atomicAdd(&curb[p.y >> 17], 1); s_out[pos] = (int)(p.y & 0x1FFFF);
        pos = atomicAdd(&curb[p.z >> 17], 1); s_out[pos] = (int)(p.z & 0x1FFFF);
        pos = atomicAdd(&curb[p.w >> 17], 1); s_out[pos] = (int)(p.w & 0x1FFFF);
    }
    for (int i = (n4 << 2) + tid; i < tot; i += 512) {
        unsigned p = stage[beg + i];
        int pos = atomicAdd(&curb[p >> 17], 1);
        s_out[pos] = (int)(p & 0x1FFFF);
    }
    __syncthreads();

    int nd = tid >> 1, half = tid & 1;
    int node = b * BW + nd;
    int rs = 0, d = 0, from = 0, to = 0;
    if (node < N) {
        rs = hs[nd]; d = h[nd];
        int d1 = ((d >> 1) + 3) & ~3; if (d1 > d) d1 = d;
        from = half ? d1 : 0;
        to   = half ? d  : d1;
    }
    float inv = 1.0f / (float)(d > 0 ? d : 1);

    // ---- layer 1: h1 = sigmoid(mean(t1) + z1) ----
    if (node < N) {
        const half8* t = (const half8*)t1;
        float s[8];
#pragma unroll
        for (int c = 0; c < 8; ++c) s[c] = 0.0f;
        int e = from;
        for (; e + 4 <= to; e += 4) {
            int4 ci = *(const int4*)(s_out + rs + e);
            half8 v0 = t[ci.x], v1 = t[ci.y], v2 = t[ci.z], v3 = t[ci.w];
#pragma unroll
            for (int c = 0; c < 8; ++c)
                s[c] += ((float)v0[c] + (float)v1[c]) + ((float)v2[c] + (float)v3[c]);
        }
        for (; e < to; ++e) {
            half8 vv = t[s_out[rs + e]];
#pragma unroll
            for (int c = 0; c < 8; ++c) s[c] += (float)vv[c];
        }
#pragma unroll
        for (int c = 0; c < 8; ++c) s[c] += __shfl_xor(s[c], 1);
        if (half == 0) {
            half8 z = ((const half8*)z1)[node];
            half8 o;
#pragma unroll
            for (int c = 0; c < 8; ++c) o[c] = (_Float16)sigmoidf_(s[c] * inv + (float)z[c]);
            ((half8*)h1)[node] = o;
        }
    }
    gbar(bar, NB);

    // ---- layer 2 + layer-3 transform ----
    if (node < N) {
        const half8* t = (const half8*)h1;
        float s[8];
#pragma unroll
        for (int c = 0; c < 8; ++c) s[c] = 0.0f;
        int e = from;
        for (; e + 4 <= to; e += 4) {
            int4 ci = *(const int4*)(s_out + rs + e);
            half8 v0 = t[ci.x], v1 = t[ci.y], v2 = t[ci.z], v3 = t[ci.w];
#pragma unroll
            for (int c = 0; c < 8; ++c)
                s[c] += ((float)v0[c] + (float)v1[c]) + ((float)v2[c] + (float)v3[c]);
        }
        for (; e < to; ++e) {
            half8 vv = t[s_out[rs + e]];
#pragma unroll
            for (int c = 0; c < 8; ++c) s[c] += (float)vv[c];
        }
#pragma unroll
        for (int c = 0; c < 8; ++c) s[c] += __shfl_xor(s[c], 1);
        float m[8];
#pragma unroll
        for (int c = 0; c < 8; ++c) m[c] = s[c] * inv;
        half8 sf = ((const half8*)h1)[node];
        float x8[8];
#pragma unroll
        for (int c = 0; c < 8; ++c) x8[c] = (float)sf[c];
        float v16[16];
#pragma unroll
        for (int j = 0; j < 16; ++j) {
            float a = sb2[j];
#pragma unroll
            for (int f = 0; f < 8; ++f)
                a += m[f] * sW2r[f * 16 + j] + x8[f] * sW2o[f * 16 + j];
            v16[j] = sigmoidf_(a);
        }
        float ta[8], za[8];
#pragma unroll
        for (int j = 0; j < 8; ++j) { ta[j] = 0.0f; za[j] = sb3[j]; }
#pragma unroll
        for (int f = 0; f < 16; ++f) {
            float hv = v16[f];
#pragma unroll
            for (int j = 0; j < 8; ++j) {
                ta[j] += hv * sW3r[f * 8 + j];
                za[j] += hv * sW3o[f * 8 + j];
            }
        }
        if (half == 0) {
            half8 th, zh;
#pragma unroll
            for (int j = 0; j < 8; ++j) { th[j] = (_Float16)ta[j]; zh[j] = (_Float16)za[j]; }
            ((half8*)t3)[node] = th;
            ((half8*)z3)[node] = zh;
        }
    }
    gbar(bar, 2 * NB);

    // ---- layer 3 + MLP head ----
    if (node < N) {
        const half8* t = (const half8*)t3;
        float s[8];
#pragma unroll
        for (int c = 0; c < 8; ++c) s[c] = 0.0f;
        int e = from;
        for (; e + 4 <= to; e += 4) {
            int4 ci = *(const int4*)(s_out + rs + e);
            half8 v0 = t[ci.x], v1 = t[ci.y], v2 = t[ci.z], v3 = t[ci.w];
#pragma unroll
            for (int c = 0; c < 8; ++c)
                s[c] += ((float)v0[c] + (float)v1[c]) + ((float)v2[c] + (float)v3[c]);
        }
        for (; e < to; ++e) {
            half8 vv = t[s_out[rs + e]];
#pragma unroll
            for (int c = 0; c < 8; ++c) s[c] += (float)vv[c];
        }
#pragma unroll
        for (int c = 0; c < 8; ++c) s[c] += __shfl_xor(s[c], 1);
        half8 z = ((const half8*)z3)[node];
        float hv8[8];
#pragma unroll
        for (int c = 0; c < 8; ++c) hv8[c] = sigmoidf_(s[c] * inv + (float)z[c]);
        float acc = sb2s[0];
#pragma unroll
        for (int j = 0; j < 32; ++j) {
            float a = sb1[j];
#pragma unroll
            for (int f = 0; f < 8; ++f) a += hv8[f] * sW1[f * 32 + j];
            acc += sW2m[j] * sigmoidf_(a);
        }
        if (half == 0) out[node] = acc;
    }
}

extern "C" void kernel_launch(void* const* d_in, const int* in_sizes, int n_in,
                              void* d_out, int out_size, void* d_ws, size_t ws_size,
                              hipStream_t stream) {
    const float* x      = (const float*)d_in[0];
    const int*   ei     = (const int*)d_in[1];
    const float* Wrel1  = (const float*)d_in[2];
    const float* b1     = (const float*)d_in[3];
    const float* Wroot1 = (const float*)d_in[4];
    const float* Wrel2  = (const float*)d_in[5];
    const float* b2     = (const float*)d_in[6];
    const float* Wroot2 = (const float*)d_in[7];
    const float* Wrel3  = (const float*)d_in[8];
    const float* b3     = (const float*)d_in[9];
    const float* Wroot3 = (const float*)d_in[10];
    const float* fc1W   = (const float*)d_in[11];
    const float* fc1b   = (const float*)d_in[12];
    const float* fc2W   = (const float*)d_in[13];
    const float* fc2b   = (const float*)d_in[14];
    float* out = (float*)d_out;

    const int N = in_sizes[0] / 16;
    const int E = in_sizes[1] / 2;
    const int* e_src = ei;
    const int* e_dst = ei + E;

    const int NB   = (N + BW - 1) / BW;           // 391
    const int NBLK = (E + CHUNK - 1) / CHUNK;     // 98
    const int nbT  = (N + 511) / 512;             // 196

    char* ws = (char*)d_ws;
    size_t off = 0;
    auto alloc = [&](size_t bytes) { char* p = ws + off; off += (bytes + 15) & ~size_t(15); return p; };
    unsigned* stage = (unsigned*)alloc((size_t)NB * REGION * 4);
    int* gcur       = (int*)alloc(((size_t)NB + 8) * 4);   // +bar slot
    int* bar        = gcur + NB;
    _Float16* t1    = (_Float16*)alloc((size_t)N * 8 * 2);
    _Float16* z1    = (_Float16*)alloc((size_t)N * 8 * 2);
    _Float16* h1    = (_Float16*)alloc((size_t)N * 8 * 2);
    _Float16* t3    = (_Float16*)alloc((size_t)N * 8 * 2);
    _Float16* z3    = (_Float16*)alloc((size_t)N * 8 * 2);

    // zero bucket cursors AND the barrier counter (re-runs every graph replay)
    hipMemsetAsync(gcur, 0, ((size_t)NB + 8) * 4, stream);

    // 1) transform1 + hist/reserve/scatter (fused, independent halves)
    setup_scatter_kernel<<<nbT + NBLK, 512, 0, stream>>>(
        x, Wrel1, b1, Wroot1, t1, z1, e_src, e_dst, gcur, stage, N, E, NB, nbT);

    // 2) mega: sort-to-LDS + 3 layers + MLP, software global barriers
    mega_kernel<<<NB, 512, 0, stream>>>(
        stage, gcur, bar, t1, z1, h1, t3, z3,
        Wrel2, b2, Wroot2, Wrel3, b3, Wroot3,
        fc1W, fc1b, fc2W, fc2b, out, N, NB);
}

// Round 13
// 256.807 us; speedup vs baseline: 1.3133x; 1.3133x over previous
//
#include <hip/hip_runtime.h>
#include <math.h>

// ---------------------------------------------------------------------------
// R12: revert to R9 structure (225.6 us measured best) + 3 targeted fixes.
//     Measured lessons:
//       R5: LDS/flat atomic feature accumulation = 183 us/layer. Never.
//       R6: node-exact global scatter = 260 us (WRITE 194 MB, 15x ampl).
//       R7: 42 B scatter runs -> 4.7x write ampl (60 MB).
//       R8: few-block big-LDS kernels = grid starvation (48.9 us).
//       R9: 225.6 us BEST. setup_scatter 48-52 us, WRITE 39-55 MB (84 B runs).
//       R11: mega-kernel fusion = 217 us ALONE (occupancy 35%, VALU 10%,
//           HBM 2%): pinning 48 KB LDS + lockstep barriers destroys the
//           latency hiding that made R9's separate kernels fast. Fusion
//           that pins LDS across gather phases is a net loss. REVERTED.
//     Changes vs R9:
//       CHUNK 16384->32768: runs 84 B -> 168 B, write-ampl floor 1.76->1.38x.
//       csr_agg1: 512 threads (2x sort throughput), layer-1 agg 4-way split.
//       gcn2/agg3: 8-way node split (grid 3125, chains halved, shfl 1,2,4).
//     Pipeline: memset + setup_scatter + csr_agg1 + gcn2 + agg3.
// ---------------------------------------------------------------------------

#define CHUNK     32768   // edges per scatter block
#define BW        128     // nodes per bucket (dst >> 7)
#define MAXNB     800     // >= NB = 782
#define MAXB_RAW  5376    // raw edges clamp per bucket (mean 4092, +20 sigma)
#define MAXB_PAD  5760    // padded rows clamp (raw + 128*3)
#define REGION    5760    // fixed region stride (ints); 16B-aligned

typedef _Float16 half8 __attribute__((ext_vector_type(8)));

static __device__ __forceinline__ float sigmoidf_(float x) {
    return 1.0f / (1.0f + expf(-x));
}

// sum of t[idx] over csr[rs+from..rs+to); from 4-aligned
static __device__ __forceinline__ void gather_sum8(
    const half8* __restrict__ t, const int* __restrict__ csr,
    int rs, int from, int to, float* s) {
#pragma unroll
    for (int c = 0; c < 8; ++c) s[c] = 0.0f;
    int e = from;
    for (; e + 4 <= to; e += 4) {
        int4 ci = *(const int4*)(csr + rs + e);
        half8 v0 = t[ci.x]; half8 v1 = t[ci.y];
        half8 v2 = t[ci.z]; half8 v3 = t[ci.w];
#pragma unroll
        for (int c = 0; c < 8; ++c)
            s[c] += ((float)v0[c] + (float)v1[c]) + ((float)v2[c] + (float)v3[c]);
    }
    for (; e < to; ++e) {
        half8 v = t[csr[rs + e]];
#pragma unroll
        for (int c = 0; c < 8; ++c) s[c] += (float)v[c];
    }
}

// 8-way split gather-mean; full mean lands on all 8 lanes of the octet
static __device__ __forceinline__ void oct_gather_mean8(
    const half8* __restrict__ t, const int* __restrict__ csr,
    int rs, int d, int oc, float* s) {
    int qs = ((d + 31) >> 5) << 2;            // 4-aligned segment >= d/8
    int from = oc * qs; if (from > d) from = d;
    int to = from + qs; if (to > d) to = d;
    gather_sum8(t, csr, rs, from, to, s);
#pragma unroll
    for (int c = 0; c < 8; ++c) s[c] += __shfl_xor(s[c], 1);
#pragma unroll
    for (int c = 0; c < 8; ++c) s[c] += __shfl_xor(s[c], 2);
#pragma unroll
    for (int c = 0; c < 8; ++c) s[c] += __shfl_xor(s[c], 4);
    float inv = 1.0f / (float)(d > 0 ? d : 1);
#pragma unroll
    for (int c = 0; c < 8; ++c) s[c] *= inv;
}

// ---- fused: transform1 (blocks [0,nbT)) + hist/reserve/scatter -----------
__global__ __launch_bounds__(512)
void setup_scatter_kernel(const float* __restrict__ x, const float* __restrict__ Wrel,
                          const float* __restrict__ bias, const float* __restrict__ Wroot,
                          _Float16* __restrict__ t1, _Float16* __restrict__ z1,
                          const int* __restrict__ src, const int* __restrict__ dst,
                          int* __restrict__ gcur, unsigned* __restrict__ stage,
                          int N, int E, int NB, int nbT) {
    __shared__ float sWr[128], sWo[128], sb[8];
    __shared__ int s_hist[MAXNB];
    __shared__ int s_cur[MAXNB];
    int tid = threadIdx.x, blk = blockIdx.x;

    if (blk < nbT) {
        // ---- transform: t1 = x@Wr1, z1 = x@Wo1 + b1 ----
        if (tid < 128) { sWr[tid] = Wrel[tid]; sWo[tid] = Wroot[tid]; }
        if (tid >= 128 && tid < 136) sb[tid - 128] = bias[tid - 128];
        __syncthreads();
        int node = blk * 512 + tid;
        if (node >= N) return;
        const float4* x4 = (const float4*)x;
        float xv[16];
#pragma unroll
        for (int k = 0; k < 4; ++k) {
            float4 v = x4[node * 4 + k];
            xv[4 * k] = v.x; xv[4 * k + 1] = v.y; xv[4 * k + 2] = v.z; xv[4 * k + 3] = v.w;
        }
        float ta[8], za[8];
#pragma unroll
        for (int j = 0; j < 8; ++j) { ta[j] = 0.0f; za[j] = sb[j]; }
#pragma unroll
        for (int f = 0; f < 16; ++f) {
            float xf = xv[f];
#pragma unroll
            for (int j = 0; j < 8; ++j) {
                ta[j] += xf * sWr[f * 8 + j];
                za[j] += xf * sWo[f * 8 + j];
            }
        }
        half8 th, zh;
#pragma unroll
        for (int j = 0; j < 8; ++j) { th[j] = (_Float16)ta[j]; zh[j] = (_Float16)za[j]; }
        ((half8*)t1)[node] = th;
        ((half8*)z1)[node] = zh;
    } else {
        // ---- per-chunk hist -> global reserve -> LDS-cursor scatter ----
        int chunk = blk - nbT;
        int base = chunk * CHUNK;
        int cnt = E - base; if (cnt > CHUNK) cnt = CHUNK;
        for (int i = tid; i < NB; i += 512) s_hist[i] = 0;
        __syncthreads();
        if (cnt == CHUNK) {
            const int4* d4 = (const int4*)(dst + base);
#pragma unroll
            for (int k = 0; k < CHUNK / 2048; ++k) {
                int4 d = d4[k * 512 + tid];
                atomicAdd(&s_hist[d.x >> 7], 1);
                atomicAdd(&s_hist[d.y >> 7], 1);
                atomicAdd(&s_hist[d.z >> 7], 1);
                atomicAdd(&s_hist[d.w >> 7], 1);
            }
        } else {
            for (int i = tid; i < cnt; i += 512) atomicAdd(&s_hist[dst[base + i] >> 7], 1);
        }
        __syncthreads();
        for (int i = tid; i < NB; i += 512) {
            int hh = s_hist[i];
            s_cur[i] = i * REGION + atomicAdd(&gcur[i], hh);
        }
        __syncthreads();
        if (cnt == CHUNK) {
            const int4* d4 = (const int4*)(dst + base);
            const int4* s4 = (const int4*)(src + base);
#pragma unroll
            for (int k = 0; k < CHUNK / 2048; ++k) {
                int4 d = d4[k * 512 + tid];
                int4 s = s4[k * 512 + tid];
                int dd[4] = {d.x, d.y, d.z, d.w};
                int ss[4] = {s.x, s.y, s.z, s.w};
#pragma unroll
                for (int j = 0; j < 4; ++j) {
                    int pos = atomicAdd(&s_cur[dd[j] >> 7], 1);
                    stage[pos] = ((unsigned)(dd[j] & 127) << 17) | (unsigned)ss[j];
                }
            }
        } else {
            for (int i = tid; i < cnt; i += 512) {
                int d = dst[base + i], s = src[base + i];
                int pos = atomicAdd(&s_cur[d >> 7], 1);
                stage[pos] = ((unsigned)(d & 127) << 17) | (unsigned)s;
            }
        }
    }
}

// ---- per-bucket counting sort (LDS) + coalesced csr + 4-way layer-1 ------
__global__ __launch_bounds__(512)
void csr_agg1_kernel(const unsigned* __restrict__ stage, const int* __restrict__ gcur,
                     int* __restrict__ csr, int* __restrict__ deg,
                     int* __restrict__ rowstart,
                     const _Float16* __restrict__ t1, const _Float16* __restrict__ z1,
                     _Float16* __restrict__ h1, int N) {
    __shared__ unsigned __attribute__((aligned(16))) s_p[MAXB_RAW];
    __shared__ int __attribute__((aligned(16))) s_out[MAXB_PAD];
    __shared__ int h[BW], hs[BW], curb[BW];
    __shared__ int s_scan[512];
    int b = blockIdx.x, tid = threadIdx.x;
    int beg = b * REGION;
    int tot = gcur[b]; if (tot > MAXB_RAW) tot = MAXB_RAW;

    // coalesced region read into LDS
    const uint4* st4 = (const uint4*)(stage + beg);
    int n4 = tot >> 2;
    for (int i = tid; i < n4; i += 512) ((uint4*)s_p)[i] = st4[i];
    for (int i = (n4 << 2) + tid; i < tot; i += 512) s_p[i] = stage[beg + i];
    if (tid < BW) h[tid] = 0;
    __syncthreads();

    // per-node histogram
    for (int i = tid; i < tot; i += 512) atomicAdd(&h[s_p[i] >> 17], 1);
    __syncthreads();

    // exclusive scan of align4(deg) via 512-ladder (zeros above BW)
    int v = (tid < BW) ? ((h[tid] + 3) & ~3) : 0;
    s_scan[tid] = v;
    for (int off = 1; off < 512; off <<= 1) {
        __syncthreads();
        int t = (tid >= off) ? s_scan[tid - off] : 0;
        __syncthreads();
        s_scan[tid] += t;
    }
    __syncthreads();
    int ptot = s_scan[511];
    if (tid < BW) {
        int myS = s_scan[tid] - v;
        hs[tid] = myS; curb[tid] = myS;
        int node = b * BW + tid;
        if (node < N) { deg[node] = h[tid]; rowstart[node] = beg + myS; }
    }
    __syncthreads();

    // counting-sort scatter into LDS s_out
    for (int i = tid; i < tot; i += 512) {
        unsigned p = s_p[i];
        int pos = atomicAdd(&curb[p >> 17], 1);
        s_out[pos] = (int)(p & 0x1FFFF);
    }
    __syncthreads();

    // coalesced csr write (ptot is a multiple of 4)
    if (ptot > MAXB_PAD) ptot = MAXB_PAD;
    int p4 = ptot >> 2;
    int4* csr4 = (int4*)(csr + beg);
    for (int i = tid; i < p4; i += 512) csr4[i] = ((const int4*)s_out)[i];

    // layer-1 aggregation: 4 threads/node, indices from LDS, t1 from L2
    int nd = tid >> 2, q = tid & 3;
    int node = b * BW + nd;
    if (node < N) {
        int rs = hs[nd], d = h[nd];
        int qs = ((d + 15) >> 4) << 2;        // 4-aligned segment >= d/4
        int from = q * qs; if (from > d) from = d;
        int to = from + qs; if (to > d) to = d;
        const half8* t = (const half8*)t1;
        float s[8];
#pragma unroll
        for (int c = 0; c < 8; ++c) s[c] = 0.0f;
        int e = from;
        for (; e + 4 <= to; e += 4) {
            int4 ci = *(const int4*)(s_out + rs + e);
            half8 v0 = t[ci.x]; half8 v1 = t[ci.y];
            half8 v2 = t[ci.z]; half8 v3 = t[ci.w];
#pragma unroll
            for (int c = 0; c < 8; ++c)
                s[c] += ((float)v0[c] + (float)v1[c]) + ((float)v2[c] + (float)v3[c]);
        }
        for (; e < to; ++e) {
            half8 vv = t[s_out[rs + e]];
#pragma unroll
            for (int c = 0; c < 8; ++c) s[c] += (float)vv[c];
        }
#pragma unroll
        for (int c = 0; c < 8; ++c) s[c] += __shfl_xor(s[c], 1);
#pragma unroll
        for (int c = 0; c < 8; ++c) s[c] += __shfl_xor(s[c], 2);
        if (q == 0) {
            float inv = 1.0f / (float)(d > 0 ? d : 1);
            half8 z = ((const half8*)z1)[node];
            half8 o;
#pragma unroll
            for (int c = 0; c < 8; ++c) o[c] = (_Float16)sigmoidf_(s[c] * inv + (float)z[c]);
            ((half8*)h1)[node] = o;
        }
    }
}

// ---- layer 2 + layer-3 transform; 8 threads per node ---------------------
__global__ __launch_bounds__(256)
void gcn2_fused_kernel(const _Float16* __restrict__ h1,
                       const int* __restrict__ rowstart, const int* __restrict__ deg,
                       const int* __restrict__ csr,
                       const float* __restrict__ W2r, const float* __restrict__ b2,
                       const float* __restrict__ W2o,
                       const float* __restrict__ W3r, const float* __restrict__ b3,
                       const float* __restrict__ W3o,
                       _Float16* __restrict__ t3, _Float16* __restrict__ z3, int n) {
    __shared__ float sW2r[128], sW2o[128], sW3r[128], sW3o[128], sb2[16], sb3[8];
    int tid = threadIdx.x;
    if (tid < 128) {
        sW2r[tid] = W2r[tid]; sW2o[tid] = W2o[tid];
        sW3r[tid] = W3r[tid]; sW3o[tid] = W3o[tid];
    }
    if (tid < 16) sb2[tid] = b2[tid];
    if (tid < 8) sb3[tid] = b3[tid];
    __syncthreads();
    int idx = blockIdx.x * 256 + tid;
    int node = idx >> 3, oc = idx & 7;
    if (node >= n) return;

    float m[8];
    oct_gather_mean8((const half8*)h1, csr, rowstart[node], deg[node], oc, m);
    half8 sf = ((const half8*)h1)[node];
    float x8[8];
#pragma unroll
    for (int c = 0; c < 8; ++c) x8[c] = (float)sf[c];

    float v16[16];
#pragma unroll
    for (int j = 0; j < 16; ++j) {
        float a = sb2[j];
#pragma unroll
        for (int f = 0; f < 8; ++f)
            a += m[f] * sW2r[f * 16 + j] + x8[f] * sW2o[f * 16 + j];
        v16[j] = sigmoidf_(a);
    }
    if (oc) return;
    float ta[8], za[8];
#pragma unroll
    for (int j = 0; j < 8; ++j) { ta[j] = 0.0f; za[j] = sb3[j]; }
#pragma unroll
    for (int f = 0; f < 16; ++f) {
        float hv = v16[f];
#pragma unroll
        for (int j = 0; j < 8; ++j) {
            ta[j] += hv * sW3r[f * 8 + j];
            za[j] += hv * sW3o[f * 8 + j];
        }
    }
    half8 th, zh;
#pragma unroll
    for (int j = 0; j < 8; ++j) { th[j] = (_Float16)ta[j]; zh[j] = (_Float16)za[j]; }
    ((half8*)t3)[node] = th;
    ((half8*)z3)[node] = zh;
}

// ---- layer 3 + full MLP head; 8 threads per node -------------------------
__global__ __launch_bounds__(256)
void agg3_mlp_kernel(const _Float16* __restrict__ t3, const _Float16* __restrict__ z3,
                     const int* __restrict__ rowstart, const int* __restrict__ deg,
                     const int* __restrict__ csr,
                     const float* __restrict__ fc1W, const float* __restrict__ fc1b,
                     const float* __restrict__ fc2W, const float* __restrict__ fc2b,
                     float* __restrict__ out, int n) {
    __shared__ float sW1[256], sb1[32], sW2[32];
    __shared__ float sb2_;
    int tid = threadIdx.x;
    if (tid < 256) sW1[tid] = fc1W[tid];
    if (tid < 32) { sb1[tid] = fc1b[tid]; sW2[tid] = fc2W[tid]; }
    if (tid == 0) sb2_ = fc2b[0];
    __syncthreads();
    int idx = blockIdx.x * 256 + tid;
    int node = idx >> 3, oc = idx & 7;
    if (node >= n) return;

    float s[8];
    oct_gather_mean8((const half8*)t3, csr, rowstart[node], deg[node], oc, s);
    if (oc) return;
    half8 z = ((const half8*)z3)[node];
    float h[8];
#pragma unroll
    for (int c = 0; c < 8; ++c) h[c] = sigmoidf_(s[c] + (float)z[c]);

    float acc = sb2_;
#pragma unroll
    for (int j = 0; j < 32; ++j) {
        float a = sb1[j];
#pragma unroll
        for (int f = 0; f < 8; ++f) a += h[f] * sW1[f * 32 + j];
        acc += sW2[j] * sigmoidf_(a);
    }
    out[node] = acc;
}

extern "C" void kernel_launch(void* const* d_in, const int* in_sizes, int n_in,
                              void* d_out, int out_size, void* d_ws, size_t ws_size,
                              hipStream_t stream) {
    const float* x      = (const float*)d_in[0];
    const int*   ei     = (const int*)d_in[1];
    const float* Wrel1  = (const float*)d_in[2];
    const float* b1     = (const float*)d_in[3];
    const float* Wroot1 = (const float*)d_in[4];
    const float* Wrel2  = (const float*)d_in[5];
    const float* b2     = (const float*)d_in[6];
    const float* Wroot2 = (const float*)d_in[7];
    const float* Wrel3  = (const float*)d_in[8];
    const float* b3     = (const float*)d_in[9];
    const float* Wroot3 = (const float*)d_in[10];
    const float* fc1W   = (const float*)d_in[11];
    const float* fc1b   = (const float*)d_in[12];
    const float* fc2W   = (const float*)d_in[13];
    const float* fc2b   = (const float*)d_in[14];
    float* out = (float*)d_out;

    const int N = in_sizes[0] / 16;
    const int E = in_sizes[1] / 2;
    const int* e_src = ei;
    const int* e_dst = ei + E;

    const int NB   = (N + BW - 1) / BW;           // 782
    const int NBLK = (E + CHUNK - 1) / CHUNK;     // 98
    const int nbT  = (N + 511) / 512;             // 196
    const int nbO  = (8 * N + 255) / 256;         // 3125 octet-split blocks

    char* ws = (char*)d_ws;
    size_t off = 0;
    auto alloc = [&](size_t bytes) { char* p = ws + off; off += (bytes + 15) & ~size_t(15); return p; };
    unsigned* stage = (unsigned*)alloc((size_t)NB * REGION * 4);
    int* csr        = (int*)alloc((size_t)NB * REGION * 4);
    int* gcur       = (int*)alloc((size_t)NB * 4);
    int* deg        = (int*)alloc((size_t)N * 4);
    int* rowstart   = (int*)alloc((size_t)N * 4);
    _Float16* t1    = (_Float16*)alloc((size_t)N * 8 * 2);
    _Float16* z1    = (_Float16*)alloc((size_t)N * 8 * 2);
    _Float16* h1    = (_Float16*)alloc((size_t)N * 8 * 2);
    _Float16* t3    = (_Float16*)alloc((size_t)N * 8 * 2);
    _Float16* z3    = (_Float16*)alloc((size_t)N * 8 * 2);

    // bucket cursors start at 0 (reserve offsets are region-relative)
    hipMemsetAsync(gcur, 0, (size_t)NB * 4, stream);

    // 1) transform1 + hist/reserve/scatter (fused, independent halves)
    setup_scatter_kernel<<<nbT + NBLK, 512, 0, stream>>>(
        x, Wrel1, b1, Wroot1, t1, z1, e_src, e_dst, gcur, stage, N, E, NB, nbT);
    // 2) per-bucket LDS counting sort -> csr (coalesced) + 4-way layer-1 agg
    csr_agg1_kernel<<<NB, 512, 0, stream>>>(stage, gcur, csr, deg, rowstart,
                                            t1, z1, h1, N);
    // 3) layer 2 + layer-3 transform (8-way split)
    gcn2_fused_kernel<<<nbO, 256, 0, stream>>>(h1, rowstart, deg, csr,
                                               Wrel2, b2, Wroot2, Wrel3, b3, Wroot3, t3, z3, N);
    // 4) layer 3 + MLP head (8-way split)
    agg3_mlp_kernel<<<nbO, 256, 0, stream>>>(t3, z3, rowstart, deg, csr,
                                             fc1W, fc1b, fc2W, fc2b, out, N);
}

// Round 14
// 226.708 us; speedup vs baseline: 1.4876x; 1.1328x over previous
//
#include <hip/hip_runtime.h>
#include <math.h>

// ---------------------------------------------------------------------------
// R13: R9 verbatim (225.6 us measured best) with ONE change: CHUNK 16384->8192.
//     Measured lessons:
//       R5: LDS/flat atomic feature accumulation = 183 us/layer. Never.
//       R6: node-exact global scatter = 260 us (WRITE 194 MB, 15x ampl).
//       R8: few-block big-LDS kernels = grid starvation (48.9 us).
//       R11: mega-kernel fusion = 217 us alone (occ 35%, pinned LDS kills
//            latency hiding). Fusion pinning LDS across gather phases: never.
//       R12: WRITE-ampl theory FALSIFIED. CHUNK 32768 cut WRITE 45->24 MB yet
//            scatter time ROSE 50->60 us (occ 5.8-7.9%, 98 blocks). Scatter is
//            a latency pipeline: time ~ 1/(resident waves), not write bytes.
//            8-way downstream split also regressed ~15 us. Both reverted.
//     This round: CHUNK 8192 -> 391 scatter blocks, 16 edges/thread (2x
//     parallelism, half the chain). WRITE will rise (~55-65 MB) - accepted.
//     Pipeline: memset + setup_scatter + csr_agg1 + gcn2 + agg3.
// ---------------------------------------------------------------------------

#define CHUNK     8192    // edges per scatter block (391 blocks)
#define BW        128     // nodes per bucket (dst >> 7)
#define MAXNB     800     // >= NB = 782
#define MAXB_RAW  5376    // raw edges clamp per bucket (mean 4092, +20 sigma)
#define MAXB_PAD  5760    // padded rows clamp (raw + 128*3)
#define REGION    5760    // fixed region stride (ints); 16B-aligned

typedef _Float16 half8 __attribute__((ext_vector_type(8)));

static __device__ __forceinline__ float sigmoidf_(float x) {
    return 1.0f / (1.0f + expf(-x));
}

// exclusive 256-scan; s[255] holds inclusive total afterwards
static __device__ __forceinline__ int scan256_excl(int v, int* s) {
    int tid = threadIdx.x;
    s[tid] = v;
    for (int off = 1; off < 256; off <<= 1) {
        __syncthreads();
        int t = (tid >= off) ? s[tid - off] : 0;
        __syncthreads();
        s[tid] += t;
    }
    __syncthreads();
    return s[tid] - v;
}

// sum of t[idx] over global csr[rs+from..rs+to); from 4-aligned
static __device__ __forceinline__ void gather_sum8(
    const half8* __restrict__ t, const int* __restrict__ csr,
    int rs, int from, int to, float* s) {
#pragma unroll
    for (int c = 0; c < 8; ++c) s[c] = 0.0f;
    int e = from;
    for (; e + 4 <= to; e += 4) {
        int4 ci = *(const int4*)(csr + rs + e);
        half8 v0 = t[ci.x]; half8 v1 = t[ci.y];
        half8 v2 = t[ci.z]; half8 v3 = t[ci.w];
#pragma unroll
        for (int c = 0; c < 8; ++c)
            s[c] += ((float)v0[c] + (float)v1[c]) + ((float)v2[c] + (float)v3[c]);
    }
    for (; e < to; ++e) {
        half8 v = t[csr[rs + e]];
#pragma unroll
        for (int c = 0; c < 8; ++c) s[c] += (float)v[c];
    }
}

// 4-way split gather-mean (agg layers 2/3); full mean lands on all 4 lanes
static __device__ __forceinline__ void quad_gather_mean8(
    const half8* __restrict__ t, const int* __restrict__ csr,
    int rs, int d, int q, float* s) {
    int qs = ((d + 15) >> 4) << 2;            // 4-aligned segment >= d/4
    int from = q * qs; if (from > d) from = d;
    int to = from + qs; if (to > d) to = d;
    gather_sum8(t, csr, rs, from, to, s);
#pragma unroll
    for (int c = 0; c < 8; ++c) s[c] += __shfl_xor(s[c], 1);
#pragma unroll
    for (int c = 0; c < 8; ++c) s[c] += __shfl_xor(s[c], 2);
    float inv = 1.0f / (float)(d > 0 ? d : 1);
#pragma unroll
    for (int c = 0; c < 8; ++c) s[c] *= inv;
}

// ---- fused: transform1 (blocks [0,nbT)) + hist/reserve/scatter -----------
__global__ __launch_bounds__(512)
void setup_scatter_kernel(const float* __restrict__ x, const float* __restrict__ Wrel,
                          const float* __restrict__ bias, const float* __restrict__ Wroot,
                          _Float16* __restrict__ t1, _Float16* __restrict__ z1,
                          const int* __restrict__ src, const int* __restrict__ dst,
                          int* __restrict__ gcur, unsigned* __restrict__ stage,
                          int N, int E, int NB, int nbT) {
    __shared__ float sWr[128], sWo[128], sb[8];
    __shared__ int s_hist[MAXNB];
    __shared__ int s_cur[MAXNB];
    int tid = threadIdx.x, blk = blockIdx.x;

    if (blk < nbT) {
        // ---- transform: t1 = x@Wr1, z1 = x@Wo1 + b1 ----
        if (tid < 128) { sWr[tid] = Wrel[tid]; sWo[tid] = Wroot[tid]; }
        if (tid >= 128 && tid < 136) sb[tid - 128] = bias[tid - 128];
        __syncthreads();
        int node = blk * 512 + tid;
        if (node >= N) return;
        const float4* x4 = (const float4*)x;
        float xv[16];
#pragma unroll
        for (int k = 0; k < 4; ++k) {
            float4 v = x4[node * 4 + k];
            xv[4 * k] = v.x; xv[4 * k + 1] = v.y; xv[4 * k + 2] = v.z; xv[4 * k + 3] = v.w;
        }
        float ta[8], za[8];
#pragma unroll
        for (int j = 0; j < 8; ++j) { ta[j] = 0.0f; za[j] = sb[j]; }
#pragma unroll
        for (int f = 0; f < 16; ++f) {
            float xf = xv[f];
#pragma unroll
            for (int j = 0; j < 8; ++j) {
                ta[j] += xf * sWr[f * 8 + j];
                za[j] += xf * sWo[f * 8 + j];
            }
        }
        half8 th, zh;
#pragma unroll
        for (int j = 0; j < 8; ++j) { th[j] = (_Float16)ta[j]; zh[j] = (_Float16)za[j]; }
        ((half8*)t1)[node] = th;
        ((half8*)z1)[node] = zh;
    } else {
        // ---- per-chunk hist -> global reserve -> LDS-cursor scatter ----
        int chunk = blk - nbT;
        int base = chunk * CHUNK;
        int cnt = E - base; if (cnt > CHUNK) cnt = CHUNK;
        for (int i = tid; i < NB; i += 512) s_hist[i] = 0;
        __syncthreads();
        if (cnt == CHUNK) {
            const int4* d4 = (const int4*)(dst + base);
#pragma unroll
            for (int k = 0; k < CHUNK / 2048; ++k) {
                int4 d = d4[k * 512 + tid];
                atomicAdd(&s_hist[d.x >> 7], 1);
                atomicAdd(&s_hist[d.y >> 7], 1);
                atomicAdd(&s_hist[d.z >> 7], 1);
                atomicAdd(&s_hist[d.w >> 7], 1);
            }
        } else {
            for (int i = tid; i < cnt; i += 512) atomicAdd(&s_hist[dst[base + i] >> 7], 1);
        }
        __syncthreads();
        for (int i = tid; i < NB; i += 512) {
            int hh = s_hist[i];
            s_cur[i] = i * REGION + atomicAdd(&gcur[i], hh);
        }
        __syncthreads();
        if (cnt == CHUNK) {
            const int4* d4 = (const int4*)(dst + base);
            const int4* s4 = (const int4*)(src + base);
#pragma unroll
            for (int k = 0; k < CHUNK / 2048; ++k) {
                int4 d = d4[k * 512 + tid];
                int4 s = s4[k * 512 + tid];
                int dd[4] = {d.x, d.y, d.z, d.w};
                int ss[4] = {s.x, s.y, s.z, s.w};
#pragma unroll
                for (int j = 0; j < 4; ++j) {
                    int pos = atomicAdd(&s_cur[dd[j] >> 7], 1);
                    stage[pos] = ((unsigned)(dd[j] & 127) << 17) | (unsigned)ss[j];
                }
            }
        } else {
            for (int i = tid; i < cnt; i += 512) {
                int d = dst[base + i], s = src[base + i];
                int pos = atomicAdd(&s_cur[d >> 7], 1);
                stage[pos] = ((unsigned)(d & 127) << 17) | (unsigned)s;
            }
        }
    }
}

// ---- per-bucket counting sort (LDS-resident) + coalesced csr + agg1 ------
__global__ __launch_bounds__(256)
void csr_agg1_kernel(const unsigned* __restrict__ stage, const int* __restrict__ gcur,
                     int* __restrict__ csr, int* __restrict__ deg,
                     int* __restrict__ rowstart,
                     const _Float16* __restrict__ t1, const _Float16* __restrict__ z1,
                     _Float16* __restrict__ h1, int N) {
    __shared__ unsigned __attribute__((aligned(16))) s_p[MAXB_RAW];
    __shared__ int __attribute__((aligned(16))) s_out[MAXB_PAD];
    __shared__ int h[BW], hs[BW], curb[BW];
    __shared__ int s_scan[256];
    int b = blockIdx.x, tid = threadIdx.x;
    int beg = b * REGION;
    int tot = gcur[b]; if (tot > MAXB_RAW) tot = MAXB_RAW;

    // coalesced region read into LDS
    const uint4* st4 = (const uint4*)(stage + beg);
    int n4 = tot >> 2;
    for (int i = tid; i < n4; i += 256) ((uint4*)s_p)[i] = st4[i];
    for (int i = (n4 << 2) + tid; i < tot; i += 256) s_p[i] = stage[beg + i];
    if (tid < BW) h[tid] = 0;
    __syncthreads();

    // per-node histogram
    for (int i = tid; i < tot; i += 256) atomicAdd(&h[s_p[i] >> 17], 1);
    __syncthreads();

    // exclusive scan of align4(deg) (tid >= BW contribute 0)
    int v = (tid < BW) ? ((h[tid] + 3) & ~3) : 0;
    int excl = scan256_excl(v, s_scan);
    int ptot = s_scan[255];
    int dg = 0, myStart = 0;
    if (tid < BW) {
        dg = h[tid]; myStart = excl;
        hs[tid] = myStart; curb[tid] = myStart;
        int node = b * BW + tid;
        if (node < N) { deg[node] = dg; rowstart[node] = beg + myStart; }
    }
    __syncthreads();

    // counting-sort scatter into LDS s_out
    for (int i = tid; i < tot; i += 256) {
        unsigned p = s_p[i];
        int pos = atomicAdd(&curb[p >> 17], 1);
        s_out[pos] = (int)(p & 0x1FFFF);
    }
    __syncthreads();

    // coalesced csr write (ptot is a multiple of 4)
    if (ptot > MAXB_PAD) ptot = MAXB_PAD;
    int p4 = ptot >> 2;
    int4* csr4 = (int4*)(csr + beg);
    for (int i = tid; i < p4; i += 256) csr4[i] = ((const int4*)s_out)[i];

    // layer-1 aggregation: 2 threads/node, indices from LDS, t1 from L2
    int nd = tid >> 1, half = tid & 1;
    int node = b * BW + nd;
    if (node < N) {
        int rs = hs[nd], d = h[nd];
        int d1 = ((d >> 1) + 3) & ~3; if (d1 > d) d1 = d;
        int from = half ? d1 : 0;
        int to   = half ? d  : d1;
        const half8* t = (const half8*)t1;
        float s[8];
#pragma unroll
        for (int c = 0; c < 8; ++c) s[c] = 0.0f;
        int e = from;
        for (; e + 4 <= to; e += 4) {
            int4 ci = *(const int4*)(s_out + rs + e);
            half8 v0 = t[ci.x]; half8 v1 = t[ci.y];
            half8 v2 = t[ci.z]; half8 v3 = t[ci.w];
#pragma unroll
            for (int c = 0; c < 8; ++c)
                s[c] += ((float)v0[c] + (float)v1[c]) + ((float)v2[c] + (float)v3[c]);
        }
        for (; e < to; ++e) {
            half8 vv = t[s_out[rs + e]];
#pragma unroll
            for (int c = 0; c < 8; ++c) s[c] += (float)vv[c];
        }
#pragma unroll
        for (int c = 0; c < 8; ++c) s[c] += __shfl_xor(s[c], 1);
        if (half == 0) {
            float inv = 1.0f / (float)(d > 0 ? d : 1);
            half8 z = ((const half8*)z1)[node];
            half8 o;
#pragma unroll
            for (int c = 0; c < 8; ++c) o[c] = (_Float16)sigmoidf_(s[c] * inv + (float)z[c]);
            ((half8*)h1)[node] = o;
        }
    }
}

// ---- layer 2 + layer-3 transform; 4 threads per node ---------------------
__global__ __launch_bounds__(256)
void gcn2_fused_kernel(const _Float16* __restrict__ h1,
                       const int* __restrict__ rowstart, const int* __restrict__ deg,
                       const int* __restrict__ csr,
                       const float* __restrict__ W2r, const float* __restrict__ b2,
                       const float* __restrict__ W2o,
                       const float* __restrict__ W3r, const float* __restrict__ b3,
                       const float* __restrict__ W3o,
                       _Float16* __restrict__ t3, _Float16* __restrict__ z3, int n) {
    __shared__ float sW2r[128], sW2o[128], sW3r[128], sW3o[128], sb2[16], sb3[8];
    int tid = threadIdx.x;
    if (tid < 128) {
        sW2r[tid] = W2r[tid]; sW2o[tid] = W2o[tid];
        sW3r[tid] = W3r[tid]; sW3o[tid] = W3o[tid];
    }
    if (tid < 16) sb2[tid] = b2[tid];
    if (tid < 8) sb3[tid] = b3[tid];
    __syncthreads();
    int idx = blockIdx.x * 256 + tid;
    int node = idx >> 2, q = idx & 3;
    if (node >= n) return;

    float m[8];
    quad_gather_mean8((const half8*)h1, csr, rowstart[node], deg[node], q, m);
    half8 sf = ((const half8*)h1)[node];
    float x8[8];
#pragma unroll
    for (int c = 0; c < 8; ++c) x8[c] = (float)sf[c];

    float v16[16];
#pragma unroll
    for (int j = 0; j < 16; ++j) {
        float a = sb2[j];
#pragma unroll
        for (int f = 0; f < 8; ++f)
            a += m[f] * sW2r[f * 16 + j] + x8[f] * sW2o[f * 16 + j];
        v16[j] = sigmoidf_(a);
    }
    float ta[8], za[8];
#pragma unroll
    for (int j = 0; j < 8; ++j) { ta[j] = 0.0f; za[j] = sb3[j]; }
#pragma unroll
    for (int f = 0; f < 16; ++f) {
        float hv = v16[f];
#pragma unroll
        for (int j = 0; j < 8; ++j) {
            ta[j] += hv * sW3r[f * 8 + j];
            za[j] += hv * sW3o[f * 8 + j];
        }
    }
    if (q) return;
    half8 th, zh;
#pragma unroll
    for (int j = 0; j < 8; ++j) { th[j] = (_Float16)ta[j]; zh[j] = (_Float16)za[j]; }
    ((half8*)t3)[node] = th;
    ((half8*)z3)[node] = zh;
}

// ---- layer 3 + full MLP head; 4 threads per node -------------------------
__global__ __launch_bounds__(256)
void agg3_mlp_kernel(const _Float16* __restrict__ t3, const _Float16* __restrict__ z3,
                     const int* __restrict__ rowstart, const int* __restrict__ deg,
                     const int* __restrict__ csr,
                     const float* __restrict__ fc1W, const float* __restrict__ fc1b,
                     const float* __restrict__ fc2W, const float* __restrict__ fc2b,
                     float* __restrict__ out, int n) {
    __shared__ float sW1[256], sb1[32], sW2[32];
    __shared__ float sb2_;
    int tid = threadIdx.x;
    if (tid < 256) sW1[tid] = fc1W[tid];
    if (tid < 32) { sb1[tid] = fc1b[tid]; sW2[tid] = fc2W[tid]; }
    if (tid == 0) sb2_ = fc2b[0];
    __syncthreads();
    int idx = blockIdx.x * 256 + tid;
    int node = idx >> 2, q = idx & 3;
    if (node >= n) return;

    float s[8];
    quad_gather_mean8((const half8*)t3, csr, rowstart[node], deg[node], q, s);
    half8 z = ((const half8*)z3)[node];
    float h[8];
#pragma unroll
    for (int c = 0; c < 8; ++c) h[c] = sigmoidf_(s[c] + (float)z[c]);

    float acc = sb2_;
#pragma unroll
    for (int j = 0; j < 32; ++j) {
        float a = sb1[j];
#pragma unroll
        for (int f = 0; f < 8; ++f) a += h[f] * sW1[f * 32 + j];
        acc += sW2[j] * sigmoidf_(a);
    }
    if (q == 0) out[node] = acc;
}

extern "C" void kernel_launch(void* const* d_in, const int* in_sizes, int n_in,
                              void* d_out, int out_size, void* d_ws, size_t ws_size,
                              hipStream_t stream) {
    const float* x      = (const float*)d_in[0];
    const int*   ei     = (const int*)d_in[1];
    const float* Wrel1  = (const float*)d_in[2];
    const float* b1     = (const float*)d_in[3];
    const float* Wroot1 = (const float*)d_in[4];
    const float* Wrel2  = (const float*)d_in[5];
    const float* b2     = (const float*)d_in[6];
    const float* Wroot2 = (const float*)d_in[7];
    const float* Wrel3  = (const float*)d_in[8];
    const float* b3     = (const float*)d_in[9];
    const float* Wroot3 = (const float*)d_in[10];
    const float* fc1W   = (const float*)d_in[11];
    const float* fc1b   = (const float*)d_in[12];
    const float* fc2W   = (const float*)d_in[13];
    const float* fc2b   = (const float*)d_in[14];
    float* out = (float*)d_out;

    const int N = in_sizes[0] / 16;
    const int E = in_sizes[1] / 2;
    const int* e_src = ei;
    const int* e_dst = ei + E;

    const int NB   = (N + BW - 1) / BW;           // 782
    const int NBLK = (E + CHUNK - 1) / CHUNK;     // 391
    const int nbT  = (N + 511) / 512;             // 196
    const int nbQ  = (4 * N + 255) / 256;         // quad-split agg blocks

    char* ws = (char*)d_ws;
    size_t off = 0;
    auto alloc = [&](size_t bytes) { char* p = ws + off; off += (bytes + 15) & ~size_t(15); return p; };
    unsigned* stage = (unsigned*)alloc((size_t)NB * REGION * 4);
    int* csr        = (int*)alloc((size_t)NB * REGION * 4);
    int* gcur       = (int*)alloc((size_t)NB * 4);
    int* deg        = (int*)alloc((size_t)N * 4);
    int* rowstart   = (int*)alloc((size_t)N * 4);
    _Float16* t1    = (_Float16*)alloc((size_t)N * 8 * 2);
    _Float16* z1    = (_Float16*)alloc((size_t)N * 8 * 2);
    _Float16* h1    = (_Float16*)alloc((size_t)N * 8 * 2);
    _Float16* t3    = (_Float16*)alloc((size_t)N * 8 * 2);
    _Float16* z3    = (_Float16*)alloc((size_t)N * 8 * 2);

    // bucket cursors start at 0 (reserve offsets are region-relative)
    hipMemsetAsync(gcur, 0, (size_t)NB * 4, stream);

    // 1) transform1 + hist/reserve/scatter (fused, independent halves)
    setup_scatter_kernel<<<nbT + NBLK, 512, 0, stream>>>(
        x, Wrel1, b1, Wroot1, t1, z1, e_src, e_dst, gcur, stage, N, E, NB, nbT);
    // 2) per-bucket LDS counting sort -> csr (coalesced) + layer-1 agg
    csr_agg1_kernel<<<NB, 256, 0, stream>>>(stage, gcur, csr, deg, rowstart,
                                            t1, z1, h1, N);
    // 3) layer 2 + layer-3 transform
    gcn2_fused_kernel<<<nbQ, 256, 0, stream>>>(h1, rowstart, deg, csr,
                                               Wrel2, b2, Wroot2, Wrel3, b3, Wroot3, t3, z3, N);
    // 4) layer 3 + MLP head
    agg3_mlp_kernel<<<nbQ, 256, 0, stream>>>(t3, z3, rowstart, deg, csr,
                                             fc1W, fc1b, fc2W, fc2b, out, N);
}